// Round 1
// baseline (880.079 us; speedup 1.0000x reference)
//
#include <hip/hip_runtime.h>
#include <hip/hip_bf16.h>
#include <cstdint>
#include <cstddef>

#define NN 100000      // nodes
#define NE 1600000     // edges
#define HH 128         // hidden dim
#define NG 256         // graphs

#define NB 196         // buckets (512 nodes each; 196*512 = 100352 >= NN)
#define BSH 9          // bucket shift
#define BMSK 511
#define CHUNK 16384    // edges per binning block
#define NBLK 98        // ceil(NE / CHUNK)

// channel-blocked "slab" layout for node features: [8 groups][NN][16 ch], bf16.
// group g of node n lives at SLAB16*g + n*16 + (c&15), uint16 units.
#define SLAB16 ((size_t)NN * 16)

typedef __bf16 bf16x8 __attribute__((ext_vector_type(8)));
typedef float floatx4 __attribute__((ext_vector_type(4)));
typedef uint32_t u32x4 __attribute__((ext_vector_type(4)));

__device__ __forceinline__ uint32_t f2b(float f) {
  union { float f; uint32_t u; } v; v.f = f;
  uint32_t u = v.u;
  return (u + 0x7FFFu + ((u >> 16) & 1u)) >> 16;   // RNE to bf16 (raw 16 bits)
}
__device__ __forceinline__ float b2f(uint32_t h) {
  union { uint32_t u; float f; } v; v.u = h << 16;
  return v.f;
}
__device__ __forceinline__ void addrow(float* a, u32x4 v) {
  a[0] += b2f(v[0] & 0xFFFFu); a[1] += b2f(v[0] >> 16);
  a[2] += b2f(v[1] & 0xFFFFu); a[3] += b2f(v[1] >> 16);
  a[4] += b2f(v[2] & 0xFFFFu); a[5] += b2f(v[2] >> 16);
  a[6] += b2f(v[3] & 0xFFFFu); a[7] += b2f(v[3] >> 16);
}

// L1-bypassing 16B gather load (sc0): random 32B strips must not allocate in L1
// nor get amplified to L1-line granularity at the L2 interface.
__device__ __forceinline__ u32x4 ld16_sc0(const uint16_t* p) {
  u32x4 v;
  asm volatile("global_load_dwordx4 %0, %1, off sc0\n\t"
               "s_waitcnt vmcnt(0)"
               : "=v"(v) : "v"(p) : "memory");
  return v;
}
__device__ __forceinline__ void ld16x4_sc0(const uint16_t* p0, const uint16_t* p1,
                                           const uint16_t* p2, const uint16_t* p3,
                                           u32x4& v0, u32x4& v1, u32x4& v2, u32x4& v3) {
  asm volatile(
      "global_load_dwordx4 %0, %4, off sc0\n\t"
      "global_load_dwordx4 %1, %5, off sc0\n\t"
      "global_load_dwordx4 %2, %6, off sc0\n\t"
      "global_load_dwordx4 %3, %7, off sc0\n\t"
      "s_waitcnt vmcnt(0)"
      : "=&v"(v0), "=&v"(v1), "=&v"(v2), "=&v"(v3)
      : "v"(p0), "v"(p1), "v"(p2), "v"(p3)
      : "memory");
}

__device__ __forceinline__ void stage_w(uint16_t (*Wt)[136], const float* __restrict__ W,
                                        int tid) {
  for (int it = 0; it < 16; ++it) {
    int idx = tid + it * 256;
    int n = idx & 127;
    int k0 = (idx >> 7) * 4;
    uint2 wv;
    wv.x = f2b(W[(k0 + 0) * 128 + n]) | (f2b(W[(k0 + 1) * 128 + n]) << 16);
    wv.y = f2b(W[(k0 + 2) * 128 + n]) | (f2b(W[(k0 + 3) * 128 + n]) << 16);
    *(uint2*)&Wt[n][k0] = wv;
  }
}

// ================= CSR build: src-bucket sort, then dst-bucket counting sort =================

__global__ __launch_bounds__(256) void k_cntA(const int* __restrict__ src,
                                              int* __restrict__ blkcnt) {
  __shared__ int h[NB];
  int t = threadIdx.x;
  if (t < NB) h[t] = 0;
  __syncthreads();
  int base = blockIdx.x * CHUNK, end = min(base + CHUNK, NE);
  for (int i = base + t; i < end; i += 256) atomicAdd(&h[src[i] >> BSH], 1);
  __syncthreads();
  if (t < NB) blkcnt[blockIdx.x * NB + t] = h[t];
}

__global__ __launch_bounds__(256) void k_cntB(const uint2* __restrict__ pairs,
                                              int* __restrict__ blkcnt) {
  __shared__ int h[NB];
  int t = threadIdx.x;
  if (t < NB) h[t] = 0;
  __syncthreads();
  int base = blockIdx.x * CHUNK, end = min(base + CHUNK, NE);
  for (int i = base + t; i < end; i += 256) atomicAdd(&h[pairs[i].y >> BSH], 1);
  __syncthreads();
  if (t < NB) blkcnt[blockIdx.x * NB + t] = h[t];
}

// merged column-scan + global-scan (replaces k_colscan + k_gscan): 1 block
__global__ void k_scan(const int* __restrict__ blkcnt, int* __restrict__ poff,
                       int* __restrict__ gbase, int* __restrict__ off, int set_off) {
  __shared__ int s[256];
  int t = threadIdx.x;
  int tot = 0;
  if (t < NB) {
    for (int r = 0; r < NBLK; ++r) {
      poff[r * NB + t] = tot;          // column-local exclusive
      tot += blkcnt[r * NB + t];
    }
  }
  s[t] = (t < NB) ? tot : 0;
  __syncthreads();
  for (int d = 1; d < 256; d <<= 1) {
    int v = (t >= d) ? s[t - d] : 0;
    __syncthreads();
    s[t] += v;
    __syncthreads();
  }
  if (t < NB) gbase[t] = s[t] - tot;
  if (t == 0) { gbase[NB] = NE; if (set_off) off[NN] = NE; }
}

__global__ __launch_bounds__(256) void k_placeA(const int* __restrict__ src,
                                                const int* __restrict__ dst,
                                                const int* __restrict__ poff,
                                                const int* __restrict__ gbase,
                                                uint2* __restrict__ pairs) {
  __shared__ int cur[NB];
  int t = threadIdx.x;
  if (t < NB) cur[t] = poff[blockIdx.x * NB + t] + gbase[t];
  __syncthreads();
  int base = blockIdx.x * CHUNK, end = min(base + CHUNK, NE);
  for (int i = base + t; i < end; i += 256) {
    int s = src[i], d = dst[i];
    int p = atomicAdd(&cur[s >> BSH], 1);
    pairs[p] = make_uint2((unsigned)s, (unsigned)d);
  }
}

__global__ __launch_bounds__(256) void k_placeB(const uint2* __restrict__ pairs,
                                                const int* __restrict__ poff,
                                                const int* __restrict__ gbase,
                                                uint32_t* __restrict__ outb) {
  __shared__ int cur[NB];
  int t = threadIdx.x;
  if (t < NB) cur[t] = poff[blockIdx.x * NB + t] + gbase[t];
  __syncthreads();
  int base = blockIdx.x * CHUNK, end = min(base + CHUNK, NE);
  for (int i = base + t; i < end; i += 256) {
    uint2 v = pairs[i];
    int p = atomicAdd(&cur[v.y >> BSH], 1);
    outb[p] = v.x | ((v.y & (unsigned)BMSK) << 17);
  }
}

// per-dst-bucket counting sort -> off/inv/csrs; fused per-block degree hist + gstart
__global__ __launch_bounds__(256) void k_bucket_sort(
    const uint32_t* __restrict__ pairbuf, const int* __restrict__ gbase,
    const int* __restrict__ batch,
    int* __restrict__ off, float* __restrict__ inv, int* __restrict__ csrs,
    int* __restrict__ dhist2, int* __restrict__ gstart)
{
  __shared__ int cnt[512];
  __shared__ int loff[512];
  __shared__ int psum[256];
  int b = blockIdx.x;
  int tid = threadIdx.x;
  cnt[tid] = 0; cnt[tid + 256] = 0;
  __syncthreads();
  int s0 = gbase[b], s1 = gbase[b + 1];
  for (int i = s0 + tid; i < s1; i += 256)
    atomicAdd(&cnt[pairbuf[i] >> 17], 1);
  __syncthreads();
  int a0 = cnt[2 * tid], a1 = cnt[2 * tid + 1];
  int s = a0 + a1;
  psum[tid] = s;
  __syncthreads();
  for (int d = 1; d < 256; d <<= 1) {
    int v = (tid >= d) ? psum[tid - d] : 0;
    __syncthreads();
    psum[tid] += v;
    __syncthreads();
  }
  int excl = psum[tid] - s;
  loff[2 * tid] = excl;
  loff[2 * tid + 1] = excl + a0;
  __syncthreads();
  int* h64 = psum;               // psum dead after excl computed
  if (tid < 64) h64[tid] = 0;
  __syncthreads();
#pragma unroll
  for (int k = 0; k < 2; ++k) {
    int i = tid + k * 256;
    int node = b * 512 + i;
    if (node < NN) {
      off[node] = s0 + loff[i];
      inv[node] = rsqrtf((float)cnt[i] + 1.0f);
      int d = cnt[i]; if (d > 63) d = 63;
      atomicAdd(&h64[d], 1);
    }
  }
  // gstart for this block's node range (batch sorted)
  {
    int n0 = b * 512, n1 = min(n0 + 512, NN);
    for (int i = n0 + tid; i < n1; i += 256) {
      int bb = batch[i];
      if (i == 0) { for (int g = 0; g <= bb; ++g) gstart[g] = 0; }
      else { int aa = batch[i - 1]; for (int g = aa + 1; g <= bb; ++g) gstart[g] = i; }
      if (i == NN - 1) { for (int g = bb + 1; g <= NG; ++g) gstart[g] = NN; }
    }
  }
  __syncthreads();
  if (tid < 64) dhist2[b * 64 + tid] = h64[tid];
  cnt[tid] = loff[tid]; cnt[tid + 256] = loff[tid + 256];   // counters -> cursors
  __syncthreads();
  for (int i = s0 + tid; i < s1; i += 256) {
    uint32_t v = pairbuf[i];
    int p = atomicAdd(&cnt[v >> 17], 1);
    csrs[s0 + p] = (int)(v & 0x1FFFFu);
  }
}

// ================= degree order: column-sum of dhist2 + descending scan (LPT) =================
__global__ void k_dscan(const int* __restrict__ dhist2, int* __restrict__ dcur) {
  int t = threadIdx.x;             // 64 threads
  int sum = 0;
  for (int r = 0; r < NB; ++r) sum += dhist2[r * 64 + (63 - t)];
  int v = sum;
  for (int d = 1; d < 64; d <<= 1) { int u = __shfl_up(v, d); if (t >= d) v += u; }
  dcur[63 - t] = v - sum;
}

__global__ __launch_bounds__(256) void k_dplace(const int* __restrict__ off,
                                                int* __restrict__ dcur,
                                                int* __restrict__ order) {
  __shared__ int h[64], base[64];
  int t = threadIdx.x;
  if (t < 64) h[t] = 0;
  __syncthreads();
  int i = blockIdx.x * 256 + t;
  int d = 0, ld = 0;
  if (i < NN) { d = off[i + 1] - off[i]; if (d > 63) d = 63; ld = atomicAdd(&h[d], 1); }
  __syncthreads();
  if (t < 64) base[t] = h[t] ? atomicAdd(&dcur[t], h[t]) : 0;
  __syncthreads();
  if (i < NN) order[base[d] + ld] = i;
}

// ================= GEMM: Out[slab] = bf16( scale[r] * (relu?(A@W + bias)) ) =================
// Operand-swapped MFMA: acc holds C^T tile -> packed uint2 stores.
// A16 / Out use the channel-blocked slab layout; A32 (raw fp32 input) is row-major.
__global__ __launch_bounds__(256) void k_gemm(
    const uint16_t* __restrict__ A16, const float* __restrict__ A32,
    const float* __restrict__ W, const float* __restrict__ bias,
    const float* __restrict__ scale,      // nullptr or per-row scale (inv)
    uint16_t* __restrict__ Out, int M, int do_relu)
{
  __shared__ uint16_t Wt[128][136];
  const int tid = threadIdx.x;
  stage_w(Wt, W, tid);
  __syncthreads();

  const int lane = tid & 63;
  const int wave = tid >> 6;
  const int lrow = lane & 15;
  const int quad = lane >> 4;
  const int lk = quad * 8;
  const int row0 = blockIdx.x * 128 + wave * 32;

  floatx4 acc[2][8];
#pragma unroll
  for (int t = 0; t < 2; ++t)
#pragma unroll
    for (int n = 0; n < 8; ++n)
      acc[t][n] = (floatx4){0.f, 0.f, 0.f, 0.f};

#pragma unroll
  for (int ks = 0; ks < 4; ++ks) {
    bf16x8 a[2];
#pragma unroll
    for (int t = 0; t < 2; ++t) {
      int r = row0 + t * 16 + lrow;
      uint4 tmp = {0u, 0u, 0u, 0u};
      if (r < M) {
        if (A32) {
          float4 f0 = *(const float4*)(A32 + (size_t)r * HH + ks * 32 + lk);
          float4 f1 = *(const float4*)(A32 + (size_t)r * HH + ks * 32 + lk + 4);
          tmp.x = f2b(f0.x) | (f2b(f0.y) << 16);
          tmp.y = f2b(f0.z) | (f2b(f0.w) << 16);
          tmp.z = f2b(f1.x) | (f2b(f1.y) << 16);
          tmp.w = f2b(f1.z) | (f2b(f1.w) << 16);
        } else {
          // slab: channels ks*32 + quad*8 .. +8 -> group ks*2 + (quad>>1), off (quad&1)*8
          tmp = *(const uint4*)(A16 + ((size_t)(ks * 2 + (quad >> 1)) * NN + r) * 16
                                + (quad & 1) * 8);
        }
      }
      a[t] = __builtin_bit_cast(bf16x8, tmp);
    }
#pragma unroll
    for (int n = 0; n < 8; ++n) {
      bf16x8 b = __builtin_bit_cast(bf16x8, *(const uint4*)&Wt[n * 16 + lrow][ks * 32 + lk]);
      acc[0][n] = __builtin_amdgcn_mfma_f32_16x16x32_bf16(b, a[0], acc[0][n], 0, 0, 0);
      acc[1][n] = __builtin_amdgcn_mfma_f32_16x16x32_bf16(b, a[1], acc[1][n], 0, 0, 0);
    }
  }

  float4 b4[8];
#pragma unroll
  for (int n = 0; n < 8; ++n) b4[n] = *(const float4*)(bias + n * 16 + quad * 4);

#pragma unroll
  for (int t = 0; t < 2; ++t) {
    int row = row0 + t * 16 + lrow;
    if (row < M) {
      float sc = scale ? scale[row] : 1.0f;
#pragma unroll
      for (int n = 0; n < 8; ++n) {
        float v0 = acc[t][n][0] + b4[n].x;
        float v1 = acc[t][n][1] + b4[n].y;
        float v2 = acc[t][n][2] + b4[n].z;
        float v3 = acc[t][n][3] + b4[n].w;
        if (do_relu) {
          v0 = fmaxf(v0, 0.f); v1 = fmaxf(v1, 0.f);
          v2 = fmaxf(v2, 0.f); v3 = fmaxf(v3, 0.f);
        }
        v0 *= sc; v1 *= sc; v2 *= sc; v3 *= sc;
        uint2 o;
        o.x = f2b(v0) | (f2b(v1) << 16);
        o.y = f2b(v2) | (f2b(v3) << 16);
        // slab: channels n*16 + quad*4 .. +4 -> group n, off quad*4
        *(uint2*)(Out + ((size_t)n * NN + row) * 16 + quad * 4) = o;
      }
    }
  }
}

// ================= fused double GEMM: Out = scale * ((A@Wa+ba) @ Wb + bb) =================
// Phase-1 result lives in an LDS tile (bf16, same rounding as the old intermediate buffer).
__global__ __launch_bounds__(256) void k_gemm_dual(
    const uint16_t* __restrict__ A16,
    const float* __restrict__ Wa, const float* __restrict__ ba,
    const float* __restrict__ Wb, const float* __restrict__ bb,
    const float* __restrict__ scale,
    uint16_t* __restrict__ Out, int M)
{
  __shared__ uint16_t Wt[128][136];
  __shared__ uint16_t tile[128][136];
  const int tid = threadIdx.x;
  stage_w(Wt, Wa, tid);
  __syncthreads();

  const int lane = tid & 63;
  const int wave = tid >> 6;
  const int lrow = lane & 15;
  const int quad = lane >> 4;
  const int lk = quad * 8;
  const int row0 = blockIdx.x * 128 + wave * 32;
  const int trow0 = wave * 32;

  floatx4 acc[2][8];
#pragma unroll
  for (int t = 0; t < 2; ++t)
#pragma unroll
    for (int n = 0; n < 8; ++n)
      acc[t][n] = (floatx4){0.f, 0.f, 0.f, 0.f};

  // phase 1: global A (slab) -> C1 (swapped layout)
#pragma unroll
  for (int ks = 0; ks < 4; ++ks) {
    bf16x8 a[2];
#pragma unroll
    for (int t = 0; t < 2; ++t) {
      int r = row0 + t * 16 + lrow;
      uint4 tmp = {0u, 0u, 0u, 0u};
      if (r < M)
        tmp = *(const uint4*)(A16 + ((size_t)(ks * 2 + (quad >> 1)) * NN + r) * 16
                              + (quad & 1) * 8);
      a[t] = __builtin_bit_cast(bf16x8, tmp);
    }
#pragma unroll
    for (int n = 0; n < 8; ++n) {
      bf16x8 b = __builtin_bit_cast(bf16x8, *(const uint4*)&Wt[n * 16 + lrow][ks * 32 + lk]);
      acc[0][n] = __builtin_amdgcn_mfma_f32_16x16x32_bf16(b, a[0], acc[0][n], 0, 0, 0);
      acc[1][n] = __builtin_amdgcn_mfma_f32_16x16x32_bf16(b, a[1], acc[1][n], 0, 0, 0);
    }
  }

  // epilogue 1 -> LDS tile (bias, no relu)
  {
    float4 b4[8];
#pragma unroll
    for (int n = 0; n < 8; ++n) b4[n] = *(const float4*)(ba + n * 16 + quad * 4);
#pragma unroll
    for (int t = 0; t < 2; ++t) {
      int trow = trow0 + t * 16 + lrow;
#pragma unroll
      for (int n = 0; n < 8; ++n) {
        uint2 o;
        o.x = f2b(acc[t][n][0] + b4[n].x) | (f2b(acc[t][n][1] + b4[n].y) << 16);
        o.y = f2b(acc[t][n][2] + b4[n].z) | (f2b(acc[t][n][3] + b4[n].w) << 16);
        *(uint2*)&tile[trow][n * 16 + quad * 4] = o;
      }
    }
  }
  __syncthreads();
  stage_w(Wt, Wb, tid);
#pragma unroll
  for (int t = 0; t < 2; ++t)
#pragma unroll
    for (int n = 0; n < 8; ++n)
      acc[t][n] = (floatx4){0.f, 0.f, 0.f, 0.f};
  __syncthreads();

  // phase 2: LDS tile A -> C2
#pragma unroll
  for (int ks = 0; ks < 4; ++ks) {
    bf16x8 a[2];
#pragma unroll
    for (int t = 0; t < 2; ++t)
      a[t] = __builtin_bit_cast(bf16x8,
               *(const uint4*)&tile[trow0 + t * 16 + lrow][ks * 32 + lk]);
#pragma unroll
    for (int n = 0; n < 8; ++n) {
      bf16x8 b = __builtin_bit_cast(bf16x8, *(const uint4*)&Wt[n * 16 + lrow][ks * 32 + lk]);
      acc[0][n] = __builtin_amdgcn_mfma_f32_16x16x32_bf16(b, a[0], acc[0][n], 0, 0, 0);
      acc[1][n] = __builtin_amdgcn_mfma_f32_16x16x32_bf16(b, a[1], acc[1][n], 0, 0, 0);
    }
  }

  // epilogue 2 -> global slab (bias, scale, no relu)
  {
    float4 b4[8];
#pragma unroll
    for (int n = 0; n < 8; ++n) b4[n] = *(const float4*)(bb + n * 16 + quad * 4);
#pragma unroll
    for (int t = 0; t < 2; ++t) {
      int row = row0 + t * 16 + lrow;
      if (row < M) {
        float sc = scale ? scale[row] : 1.0f;
#pragma unroll
        for (int n = 0; n < 8; ++n) {
          float v0 = (acc[t][n][0] + b4[n].x) * sc;
          float v1 = (acc[t][n][1] + b4[n].y) * sc;
          float v2 = (acc[t][n][2] + b4[n].z) * sc;
          float v3 = (acc[t][n][3] + b4[n].w) * sc;
          uint2 o;
          o.x = f2b(v0) | (f2b(v1) << 16);
          o.y = f2b(v2) | (f2b(v3) << 16);
          *(uint2*)(Out + ((size_t)n * NN + row) * 16 + quad * 4) = o;
        }
      }
    }
  }
}

// ================= aggregation: XCD-pinned channel-group gather-sum =================
// blockIdx.x & 7 = channel group g -> lands on XCD g (round-robin dispatch).
// XCD g only ever touches slab g: NN*32B = 3.2 MB < 4 MiB per-XCD L2 -> gathers hit L2.
// 2 lanes per node (16B each); csrs index reads split across the lane pair + shfl.
__global__ __launch_bounds__(256) void k_agg(
    const uint16_t* __restrict__ hw2, const int* __restrict__ off,
    const int* __restrict__ csrs, const float* __restrict__ inv,
    const int* __restrict__ order,
    uint16_t* __restrict__ hout, int do_relu)
{
  const int g = blockIdx.x & 7;
  const int slot = (blockIdx.x >> 3) * 128 + (threadIdx.x >> 1);
  if (slot >= NN) return;
  const int p = threadIdx.x & 1;
  const int node = order[slot];

  const uint16_t* base = hw2 + (size_t)g * SLAB16;
  float a[8] = {0.f, 0.f, 0.f, 0.f, 0.f, 0.f, 0.f, 0.f};

  // self term (already inv[node]-prescaled by the producing GEMM)
  addrow(a, ld16_sc0(base + (size_t)node * 16 + p * 8));

  const int e0 = off[node], e1 = off[node + 1];
  int e = e0;
  for (; e + 4 <= e1; e += 4) {
    // lane p loads indices e+2p, e+2p+1; partner exchange covers all 4 (order
    // within the 4-group is commutative in the fp32 accumulator).
    int i0 = __builtin_nontemporal_load(csrs + e + 2 * p);
    int i1 = __builtin_nontemporal_load(csrs + e + 2 * p + 1);
    int j0 = __shfl_xor(i0, 1);
    int j1 = __shfl_xor(i1, 1);
    u32x4 v0, v1, v2, v3;
    ld16x4_sc0(base + (size_t)i0 * 16 + p * 8, base + (size_t)i1 * 16 + p * 8,
               base + (size_t)j0 * 16 + p * 8, base + (size_t)j1 * 16 + p * 8,
               v0, v1, v2, v3);
    addrow(a, v0); addrow(a, v1); addrow(a, v2); addrow(a, v3);
  }
  for (; e < e1; ++e) {
    int s = __builtin_nontemporal_load(csrs + e);
    addrow(a, ld16_sc0(base + (size_t)s * 16 + p * 8));
  }

  float invd = inv[node];
#pragma unroll
  for (int j = 0; j < 8; ++j) {
    a[j] *= invd;
    if (do_relu) a[j] = fmaxf(a[j], 0.f);
  }
  u32x4 o;
  o[0] = f2b(a[0]) | (f2b(a[1]) << 16);
  o[1] = f2b(a[2]) | (f2b(a[3]) << 16);
  o[2] = f2b(a[4]) | (f2b(a[5]) << 16);
  o[3] = f2b(a[6]) | (f2b(a[7]) << 16);
  // non-temporal: don't evict the resident source slab
  __builtin_nontemporal_store(o, (u32x4*)(hout + (size_t)g * SLAB16 + (size_t)node * 16 + p * 8));
}

// ================= fused pool + decoder: one block per graph, zero atomics =================
__global__ __launch_bounds__(256) void k_pooldec(
    const uint16_t* __restrict__ h, const int* __restrict__ gstart,
    const float* __restrict__ w1, const float* __restrict__ b1,
    const float* __restrict__ w2, const float* __restrict__ b2,
    float* __restrict__ out)
{
  __shared__ float red[16][132];   // +4 pad
  __shared__ float p[128], tmpv[128];
  int g = blockIdx.x;
  int tid = threadIdx.x;
  int slot = tid >> 4;
  int c = (tid & 15) * 8;
  // slab addressing for this thread's 8 channels
  const uint16_t* hp = h + (size_t)(c >> 4) * SLAB16 + (c & 15);

  int r0 = gstart[g], r1 = gstart[g + 1];
  float a[8] = {0.f, 0.f, 0.f, 0.f, 0.f, 0.f, 0.f, 0.f};
  for (int r = r0 + slot; r < r1; r += 16) {
    uint4 v = *(const uint4*)(hp + (size_t)r * 16);
    a[0] += b2f(v.x & 0xFFFFu); a[1] += b2f(v.x >> 16);
    a[2] += b2f(v.y & 0xFFFFu); a[3] += b2f(v.y >> 16);
    a[4] += b2f(v.z & 0xFFFFu); a[5] += b2f(v.z >> 16);
    a[6] += b2f(v.w & 0xFFFFu); a[7] += b2f(v.w >> 16);
  }
  *(float4*)&red[slot][c]     = make_float4(a[0], a[1], a[2], a[3]);
  *(float4*)&red[slot][c + 4] = make_float4(a[4], a[5], a[6], a[7]);
  __syncthreads();
  if (tid < 128) {
    float s = 0.f;
#pragma unroll
    for (int k = 0; k < 16; ++k) s += red[k][tid];
    p[tid] = s;
  }
  __syncthreads();
  if (tid < 128) {
    float acc1 = b1[tid];
    for (int k = 0; k < 128; ++k) acc1 += p[k] * w1[k * 128 + tid];
    tmpv[tid] = fmaxf(acc1, 0.f);
  }
  __syncthreads();
  if (tid < 10) {
    float o = b2[tid];
    for (int k = 0; k < 128; ++k) o += tmpv[k] * w2[k * 10 + tid];
    out[g * 10 + tid] = o;
  }
}

extern "C" void kernel_launch(void* const* d_in, const int* in_sizes, int n_in,
                              void* d_out, int out_size, void* d_ws, size_t ws_size,
                              hipStream_t stream) {
  const float* x       = (const float*)d_in[0];
  const int*   eidx    = (const int*)d_in[1];
  const int*   src     = eidx;            // edge_index[0]
  const int*   dst     = eidx + NE;       // edge_index[1]
  const int*   batch   = (const int*)d_in[3];
  const float* enc_w1  = (const float*)d_in[4];
  const float* enc_b1  = (const float*)d_in[5];
  const float* enc_w2  = (const float*)d_in[6];
  const float* enc_b2  = (const float*)d_in[7];
  const float* conv_w  = (const float*)d_in[8];
  const float* conv_b  = (const float*)d_in[9];
  const float* dec_w1  = (const float*)d_in[10];
  const float* dec_b1  = (const float*)d_in[11];
  const float* dec_w2  = (const float*)d_in[12];
  const float* dec_b2  = (const float*)d_in[13];
  float* out = (float*)d_out;

  char* ws = (char*)d_ws;
  size_t o = 0;
  auto alloc = [&](size_t bytes) -> char* {
    char* p = ws + o;
    o += (bytes + 255) & ~(size_t)255;
    return p;
  };
  int*      off     = (int*)alloc((size_t)(NN + 1) * 4);
  int*      csrs    = (int*)alloc((size_t)NE * 4);
  float*    inv     = (float*)alloc((size_t)NN * 4);
  int*      blkcntA = (int*)alloc((size_t)NBLK * NB * 4);
  int*      poffA   = (int*)alloc((size_t)NBLK * NB * 4);
  int*      blkcntB = (int*)alloc((size_t)NBLK * NB * 4);
  int*      poffB   = (int*)alloc((size_t)NBLK * NB * 4);
  int*      gbaseA  = (int*)alloc((size_t)(NB + 1) * 4);
  int*      gbaseB  = (int*)alloc((size_t)(NB + 1) * 4);
  int*      dhist2  = (int*)alloc((size_t)NB * 64 * 4);
  int*      dcur    = (int*)alloc(64 * 4);
  int*      order   = (int*)alloc((size_t)NN * 4);
  int*      gstart  = (int*)alloc((size_t)(NG + 1) * 4);
  uint16_t* buf0    = (uint16_t*)alloc((size_t)NN * HH * 2);
  uint16_t* buf1    = (uint16_t*)alloc((size_t)NN * HH * 2);
  uint2*    pairsA  = (uint2*)buf1;                          // 12.8 MB, dead before encoder
  uint32_t* pairB   = (uint32_t*)((char*)buf1 + (size_t)NE * 8);  // +6.4 MB, still < 25.6 MB

  // CSR build: sort by src-bucket, then stable by dst-bucket, then per-bucket by dst node
  k_cntA<<<dim3(NBLK), dim3(256), 0, stream>>>(src, blkcntA);
  k_scan<<<dim3(1), dim3(256), 0, stream>>>(blkcntA, poffA, gbaseA, off, 0);
  k_placeA<<<dim3(NBLK), dim3(256), 0, stream>>>(src, dst, poffA, gbaseA, pairsA);
  k_cntB<<<dim3(NBLK), dim3(256), 0, stream>>>(pairsA, blkcntB);
  k_scan<<<dim3(1), dim3(256), 0, stream>>>(blkcntB, poffB, gbaseB, off, 1);
  k_placeB<<<dim3(NBLK), dim3(256), 0, stream>>>(pairsA, poffB, gbaseB, pairB);
  k_bucket_sort<<<dim3(NB), dim3(256), 0, stream>>>(pairB, gbaseB, batch, off, inv, csrs,
                                                    dhist2, gstart);

  // degree-LPT order
  const int NBK = (NN + 255) / 256;
  k_dscan<<<dim3(1), dim3(64), 0, stream>>>(dhist2, dcur);
  k_dplace<<<dim3(NBK), dim3(256), 0, stream>>>(off, dcur, order);

  // encoder GEMM1 (fp32 x), then fused [enc2 + conv0 + prescale]
  const int GB = (NN + 127) / 128;   // 782
  k_gemm<<<dim3(GB), dim3(256), 0, stream>>>(nullptr, x, enc_w1, enc_b1, nullptr, buf1, NN, 1);
  k_gemm_dual<<<dim3(GB), dim3(256), 0, stream>>>(buf1, enc_w2, enc_b2,
                                                  conv_w + 0 * 16384, conv_b + 0,
                                                  inv, buf0, NN);

  // GCN layers: agg (XCD-pinned channel slabs) alternating with prescaled conv GEMMs
  const int AGB = 8 * ((NN + 127) / 128);   // 8 channel groups x 782 node chunks
  k_agg <<<dim3(AGB), dim3(256), 0, stream>>>(buf0, off, csrs, inv, order, buf1, 1);
  k_gemm<<<dim3(GB), dim3(256), 0, stream>>>(buf1, nullptr, conv_w + 1 * 16384, conv_b + 128, inv, buf0, NN, 0);
  k_agg <<<dim3(AGB), dim3(256), 0, stream>>>(buf0, off, csrs, inv, order, buf1, 1);
  k_gemm<<<dim3(GB), dim3(256), 0, stream>>>(buf1, nullptr, conv_w + 2 * 16384, conv_b + 256, inv, buf0, NN, 0);
  k_agg <<<dim3(AGB), dim3(256), 0, stream>>>(buf0, off, csrs, inv, order, buf1, 0);

  // fused pool + decoder
  k_pooldec<<<dim3(NG), dim3(256), 0, stream>>>(buf1, gstart, dec_w1, dec_b1, dec_w2, dec_b2, out);
}

// Round 2
// 517.000 us; speedup vs baseline: 1.7023x; 1.7023x over previous
//
#include <hip/hip_runtime.h>
#include <hip/hip_bf16.h>
#include <cstdint>
#include <cstddef>

#define NN 100000      // nodes
#define NE 1600000     // edges
#define HH 128         // hidden dim
#define NG 256         // graphs

#define NB 196         // buckets (512 nodes each; 196*512 = 100352 >= NN)
#define BSH 9          // bucket shift
#define BMSK 511
#define CHUNK 16384    // edges per binning block
#define NBLK 98        // ceil(NE / CHUNK)

typedef __bf16 bf16x8 __attribute__((ext_vector_type(8)));
typedef float floatx4 __attribute__((ext_vector_type(4)));

__device__ __forceinline__ uint32_t f2b(float f) {
  union { float f; uint32_t u; } v; v.f = f;
  uint32_t u = v.u;
  return (u + 0x7FFFu + ((u >> 16) & 1u)) >> 16;   // RNE to bf16 (raw 16 bits)
}
__device__ __forceinline__ float b2f(uint32_t h) {
  union { uint32_t u; float f; } v; v.u = h << 16;
  return v.f;
}
__device__ __forceinline__ void addrow(float* a, uint4 v) {
  a[0] += b2f(v.x & 0xFFFFu); a[1] += b2f(v.x >> 16);
  a[2] += b2f(v.y & 0xFFFFu); a[3] += b2f(v.y >> 16);
  a[4] += b2f(v.z & 0xFFFFu); a[5] += b2f(v.z >> 16);
  a[6] += b2f(v.w & 0xFFFFu); a[7] += b2f(v.w >> 16);
}

__device__ __forceinline__ void stage_w(uint16_t (*Wt)[136], const float* __restrict__ W,
                                        int tid) {
  for (int it = 0; it < 16; ++it) {
    int idx = tid + it * 256;
    int n = idx & 127;
    int k0 = (idx >> 7) * 4;
    uint2 wv;
    wv.x = f2b(W[(k0 + 0) * 128 + n]) | (f2b(W[(k0 + 1) * 128 + n]) << 16);
    wv.y = f2b(W[(k0 + 2) * 128 + n]) | (f2b(W[(k0 + 3) * 128 + n]) << 16);
    *(uint2*)&Wt[n][k0] = wv;
  }
}

// ================= CSR build: src-bucket sort, then dst-bucket counting sort =================

__global__ __launch_bounds__(256) void k_cntA(const int* __restrict__ src,
                                              int* __restrict__ blkcnt) {
  __shared__ int h[NB];
  int t = threadIdx.x;
  if (t < NB) h[t] = 0;
  __syncthreads();
  int base = blockIdx.x * CHUNK, end = min(base + CHUNK, NE);
  for (int i = base + t; i < end; i += 256) atomicAdd(&h[src[i] >> BSH], 1);
  __syncthreads();
  if (t < NB) blkcnt[blockIdx.x * NB + t] = h[t];
}

__global__ __launch_bounds__(256) void k_cntB(const uint2* __restrict__ pairs,
                                              int* __restrict__ blkcnt) {
  __shared__ int h[NB];
  int t = threadIdx.x;
  if (t < NB) h[t] = 0;
  __syncthreads();
  int base = blockIdx.x * CHUNK, end = min(base + CHUNK, NE);
  for (int i = base + t; i < end; i += 256) atomicAdd(&h[pairs[i].y >> BSH], 1);
  __syncthreads();
  if (t < NB) blkcnt[blockIdx.x * NB + t] = h[t];
}

// merged column-scan + global-scan: 1 block
__global__ void k_scan(const int* __restrict__ blkcnt, int* __restrict__ poff,
                       int* __restrict__ gbase, int* __restrict__ off, int set_off) {
  __shared__ int s[256];
  int t = threadIdx.x;
  int tot = 0;
  if (t < NB) {
    for (int r = 0; r < NBLK; ++r) {
      poff[r * NB + t] = tot;          // column-local exclusive
      tot += blkcnt[r * NB + t];
    }
  }
  s[t] = (t < NB) ? tot : 0;
  __syncthreads();
  for (int d = 1; d < 256; d <<= 1) {
    int v = (t >= d) ? s[t - d] : 0;
    __syncthreads();
    s[t] += v;
    __syncthreads();
  }
  if (t < NB) gbase[t] = s[t] - tot;
  if (t == 0) { gbase[NB] = NE; if (set_off) off[NN] = NE; }
}

__global__ __launch_bounds__(256) void k_placeA(const int* __restrict__ src,
                                                const int* __restrict__ dst,
                                                const int* __restrict__ poff,
                                                const int* __restrict__ gbase,
                                                uint2* __restrict__ pairs) {
  __shared__ int cur[NB];
  int t = threadIdx.x;
  if (t < NB) cur[t] = poff[blockIdx.x * NB + t] + gbase[t];
  __syncthreads();
  int base = blockIdx.x * CHUNK, end = min(base + CHUNK, NE);
  for (int i = base + t; i < end; i += 256) {
    int s = src[i], d = dst[i];
    int p = atomicAdd(&cur[s >> BSH], 1);
    pairs[p] = make_uint2((unsigned)s, (unsigned)d);
  }
}

__global__ __launch_bounds__(256) void k_placeB(const uint2* __restrict__ pairs,
                                                const int* __restrict__ poff,
                                                const int* __restrict__ gbase,
                                                uint32_t* __restrict__ outb) {
  __shared__ int cur[NB];
  int t = threadIdx.x;
  if (t < NB) cur[t] = poff[blockIdx.x * NB + t] + gbase[t];
  __syncthreads();
  int base = blockIdx.x * CHUNK, end = min(base + CHUNK, NE);
  for (int i = base + t; i < end; i += 256) {
    uint2 v = pairs[i];
    int p = atomicAdd(&cur[v.y >> BSH], 1);
    outb[p] = v.x | ((v.y & (unsigned)BMSK) << 17);
  }
}

// per-dst-bucket counting sort -> off/inv/csrs; fused per-block degree hist + gstart
__global__ __launch_bounds__(256) void k_bucket_sort(
    const uint32_t* __restrict__ pairbuf, const int* __restrict__ gbase,
    const int* __restrict__ batch,
    int* __restrict__ off, float* __restrict__ inv, int* __restrict__ csrs,
    int* __restrict__ dhist2, int* __restrict__ gstart)
{
  __shared__ int cnt[512];
  __shared__ int loff[512];
  __shared__ int psum[256];
  int b = blockIdx.x;
  int tid = threadIdx.x;
  cnt[tid] = 0; cnt[tid + 256] = 0;
  __syncthreads();
  int s0 = gbase[b], s1 = gbase[b + 1];
  for (int i = s0 + tid; i < s1; i += 256)
    atomicAdd(&cnt[pairbuf[i] >> 17], 1);
  __syncthreads();
  int a0 = cnt[2 * tid], a1 = cnt[2 * tid + 1];
  int s = a0 + a1;
  psum[tid] = s;
  __syncthreads();
  for (int d = 1; d < 256; d <<= 1) {
    int v = (tid >= d) ? psum[tid - d] : 0;
    __syncthreads();
    psum[tid] += v;
    __syncthreads();
  }
  int excl = psum[tid] - s;
  loff[2 * tid] = excl;
  loff[2 * tid + 1] = excl + a0;
  __syncthreads();
  int* h64 = psum;               // psum dead after excl computed
  if (tid < 64) h64[tid] = 0;
  __syncthreads();
#pragma unroll
  for (int k = 0; k < 2; ++k) {
    int i = tid + k * 256;
    int node = b * 512 + i;
    if (node < NN) {
      off[node] = s0 + loff[i];
      inv[node] = rsqrtf((float)cnt[i] + 1.0f);
      int d = cnt[i]; if (d > 63) d = 63;
      atomicAdd(&h64[d], 1);
    }
  }
  // gstart for this block's node range (batch sorted)
  {
    int n0 = b * 512, n1 = min(n0 + 512, NN);
    for (int i = n0 + tid; i < n1; i += 256) {
      int bb = batch[i];
      if (i == 0) { for (int g = 0; g <= bb; ++g) gstart[g] = 0; }
      else { int aa = batch[i - 1]; for (int g = aa + 1; g <= bb; ++g) gstart[g] = i; }
      if (i == NN - 1) { for (int g = bb + 1; g <= NG; ++g) gstart[g] = NN; }
    }
  }
  __syncthreads();
  if (tid < 64) dhist2[b * 64 + tid] = h64[tid];
  cnt[tid] = loff[tid]; cnt[tid + 256] = loff[tid + 256];   // counters -> cursors
  __syncthreads();
  for (int i = s0 + tid; i < s1; i += 256) {
    uint32_t v = pairbuf[i];
    int p = atomicAdd(&cnt[v >> 17], 1);
    csrs[s0 + p] = (int)(v & 0x1FFFFu);
  }
}

// ================= degree order: column-sum of dhist2 + descending scan (LPT) =================
__global__ void k_dscan(const int* __restrict__ dhist2, int* __restrict__ dcur) {
  int t = threadIdx.x;             // 64 threads
  int sum = 0;
  for (int r = 0; r < NB; ++r) sum += dhist2[r * 64 + (63 - t)];
  int v = sum;
  for (int d = 1; d < 64; d <<= 1) { int u = __shfl_up(v, d); if (t >= d) v += u; }
  dcur[63 - t] = v - sum;
}

__global__ __launch_bounds__(256) void k_dplace(const int* __restrict__ off,
                                                int* __restrict__ dcur,
                                                int* __restrict__ order) {
  __shared__ int h[64], base[64];
  int t = threadIdx.x;
  if (t < 64) h[t] = 0;
  __syncthreads();
  int i = blockIdx.x * 256 + t;
  int d = 0, ld = 0;
  if (i < NN) { d = off[i + 1] - off[i]; if (d > 63) d = 63; ld = atomicAdd(&h[d], 1); }
  __syncthreads();
  if (t < 64) base[t] = h[t] ? atomicAdd(&dcur[t], h[t]) : 0;
  __syncthreads();
  if (i < NN) order[base[d] + ld] = i;
}

// ================= GEMM: Out[M,128] = bf16( scale[r] * (relu?(A@W + bias)) ) =================
// Operand-swapped MFMA: acc holds C^T tile -> packed uint2 stores.
__global__ __launch_bounds__(256) void k_gemm(
    const uint16_t* __restrict__ A16, const float* __restrict__ A32,
    const float* __restrict__ W, const float* __restrict__ bias,
    const float* __restrict__ scale,      // nullptr or per-row scale (inv)
    uint16_t* __restrict__ Out, int M, int do_relu)
{
  __shared__ uint16_t Wt[128][136];
  const int tid = threadIdx.x;
  stage_w(Wt, W, tid);
  __syncthreads();

  const int lane = tid & 63;
  const int wave = tid >> 6;
  const int lrow = lane & 15;
  const int quad = lane >> 4;
  const int lk = quad * 8;
  const int row0 = blockIdx.x * 128 + wave * 32;

  floatx4 acc[2][8];
#pragma unroll
  for (int t = 0; t < 2; ++t)
#pragma unroll
    for (int n = 0; n < 8; ++n)
      acc[t][n] = (floatx4){0.f, 0.f, 0.f, 0.f};

#pragma unroll
  for (int ks = 0; ks < 4; ++ks) {
    bf16x8 a[2];
#pragma unroll
    for (int t = 0; t < 2; ++t) {
      int r = row0 + t * 16 + lrow;
      uint4 tmp = {0u, 0u, 0u, 0u};
      if (r < M) {
        if (A32) {
          float4 f0 = *(const float4*)(A32 + (size_t)r * HH + ks * 32 + lk);
          float4 f1 = *(const float4*)(A32 + (size_t)r * HH + ks * 32 + lk + 4);
          tmp.x = f2b(f0.x) | (f2b(f0.y) << 16);
          tmp.y = f2b(f0.z) | (f2b(f0.w) << 16);
          tmp.z = f2b(f1.x) | (f2b(f1.y) << 16);
          tmp.w = f2b(f1.z) | (f2b(f1.w) << 16);
        } else {
          tmp = *(const uint4*)(A16 + (size_t)r * HH + ks * 32 + lk);
        }
      }
      a[t] = __builtin_bit_cast(bf16x8, tmp);
    }
#pragma unroll
    for (int n = 0; n < 8; ++n) {
      bf16x8 b = __builtin_bit_cast(bf16x8, *(const uint4*)&Wt[n * 16 + lrow][ks * 32 + lk]);
      acc[0][n] = __builtin_amdgcn_mfma_f32_16x16x32_bf16(b, a[0], acc[0][n], 0, 0, 0);
      acc[1][n] = __builtin_amdgcn_mfma_f32_16x16x32_bf16(b, a[1], acc[1][n], 0, 0, 0);
    }
  }

  float4 b4[8];
#pragma unroll
  for (int n = 0; n < 8; ++n) b4[n] = *(const float4*)(bias + n * 16 + quad * 4);

#pragma unroll
  for (int t = 0; t < 2; ++t) {
    int row = row0 + t * 16 + lrow;
    if (row < M) {
      float sc = scale ? scale[row] : 1.0f;
      uint16_t* orow = Out + (size_t)row * HH;
#pragma unroll
      for (int n = 0; n < 8; ++n) {
        float v0 = acc[t][n][0] + b4[n].x;
        float v1 = acc[t][n][1] + b4[n].y;
        float v2 = acc[t][n][2] + b4[n].z;
        float v3 = acc[t][n][3] + b4[n].w;
        if (do_relu) {
          v0 = fmaxf(v0, 0.f); v1 = fmaxf(v1, 0.f);
          v2 = fmaxf(v2, 0.f); v3 = fmaxf(v3, 0.f);
        }
        v0 *= sc; v1 *= sc; v2 *= sc; v3 *= sc;
        uint2 o;
        o.x = f2b(v0) | (f2b(v1) << 16);
        o.y = f2b(v2) | (f2b(v3) << 16);
        *(uint2*)(orow + n * 16 + quad * 4) = o;
      }
    }
  }
}

// ================= fused double GEMM: Out = scale * ((A@Wa+ba) @ Wb + bb) =================
__global__ __launch_bounds__(256) void k_gemm_dual(
    const uint16_t* __restrict__ A16,
    const float* __restrict__ Wa, const float* __restrict__ ba,
    const float* __restrict__ Wb, const float* __restrict__ bb,
    const float* __restrict__ scale,
    uint16_t* __restrict__ Out, int M)
{
  __shared__ uint16_t Wt[128][136];
  __shared__ uint16_t tile[128][136];
  const int tid = threadIdx.x;
  stage_w(Wt, Wa, tid);
  __syncthreads();

  const int lane = tid & 63;
  const int wave = tid >> 6;
  const int lrow = lane & 15;
  const int quad = lane >> 4;
  const int lk = quad * 8;
  const int row0 = blockIdx.x * 128 + wave * 32;
  const int trow0 = wave * 32;

  floatx4 acc[2][8];
#pragma unroll
  for (int t = 0; t < 2; ++t)
#pragma unroll
    for (int n = 0; n < 8; ++n)
      acc[t][n] = (floatx4){0.f, 0.f, 0.f, 0.f};

  // phase 1: global A -> C1 (swapped layout)
#pragma unroll
  for (int ks = 0; ks < 4; ++ks) {
    bf16x8 a[2];
#pragma unroll
    for (int t = 0; t < 2; ++t) {
      int r = row0 + t * 16 + lrow;
      uint4 tmp = {0u, 0u, 0u, 0u};
      if (r < M) tmp = *(const uint4*)(A16 + (size_t)r * HH + ks * 32 + lk);
      a[t] = __builtin_bit_cast(bf16x8, tmp);
    }
#pragma unroll
    for (int n = 0; n < 8; ++n) {
      bf16x8 b = __builtin_bit_cast(bf16x8, *(const uint4*)&Wt[n * 16 + lrow][ks * 32 + lk]);
      acc[0][n] = __builtin_amdgcn_mfma_f32_16x16x32_bf16(b, a[0], acc[0][n], 0, 0, 0);
      acc[1][n] = __builtin_amdgcn_mfma_f32_16x16x32_bf16(b, a[1], acc[1][n], 0, 0, 0);
    }
  }

  // epilogue 1 -> LDS tile (bias, no relu)
  {
    float4 b4[8];
#pragma unroll
    for (int n = 0; n < 8; ++n) b4[n] = *(const float4*)(ba + n * 16 + quad * 4);
#pragma unroll
    for (int t = 0; t < 2; ++t) {
      int trow = trow0 + t * 16 + lrow;
#pragma unroll
      for (int n = 0; n < 8; ++n) {
        uint2 o;
        o.x = f2b(acc[t][n][0] + b4[n].x) | (f2b(acc[t][n][1] + b4[n].y) << 16);
        o.y = f2b(acc[t][n][2] + b4[n].z) | (f2b(acc[t][n][3] + b4[n].w) << 16);
        *(uint2*)&tile[trow][n * 16 + quad * 4] = o;
      }
    }
  }
  __syncthreads();
  stage_w(Wt, Wb, tid);
#pragma unroll
  for (int t = 0; t < 2; ++t)
#pragma unroll
    for (int n = 0; n < 8; ++n)
      acc[t][n] = (floatx4){0.f, 0.f, 0.f, 0.f};
  __syncthreads();

  // phase 2: LDS tile A -> C2
#pragma unroll
  for (int ks = 0; ks < 4; ++ks) {
    bf16x8 a[2];
#pragma unroll
    for (int t = 0; t < 2; ++t)
      a[t] = __builtin_bit_cast(bf16x8,
               *(const uint4*)&tile[trow0 + t * 16 + lrow][ks * 32 + lk]);
#pragma unroll
    for (int n = 0; n < 8; ++n) {
      bf16x8 b = __builtin_bit_cast(bf16x8, *(const uint4*)&Wt[n * 16 + lrow][ks * 32 + lk]);
      acc[0][n] = __builtin_amdgcn_mfma_f32_16x16x32_bf16(b, a[0], acc[0][n], 0, 0, 0);
      acc[1][n] = __builtin_amdgcn_mfma_f32_16x16x32_bf16(b, a[1], acc[1][n], 0, 0, 0);
    }
  }

  // epilogue 2 -> global (bias, scale, no relu)
  {
    float4 b4[8];
#pragma unroll
    for (int n = 0; n < 8; ++n) b4[n] = *(const float4*)(bb + n * 16 + quad * 4);
#pragma unroll
    for (int t = 0; t < 2; ++t) {
      int row = row0 + t * 16 + lrow;
      if (row < M) {
        float sc = scale ? scale[row] : 1.0f;
        uint16_t* orow = Out + (size_t)row * HH;
#pragma unroll
        for (int n = 0; n < 8; ++n) {
          float v0 = (acc[t][n][0] + b4[n].x) * sc;
          float v1 = (acc[t][n][1] + b4[n].y) * sc;
          float v2 = (acc[t][n][2] + b4[n].z) * sc;
          float v3 = (acc[t][n][3] + b4[n].w) * sc;
          uint2 o;
          o.x = f2b(v0) | (f2b(v1) << 16);
          o.y = f2b(v2) | (f2b(v3) << 16);
          *(uint2*)(orow + n * 16 + quad * 4) = o;
        }
      }
    }
  }
}

// ================= aggregation: half-channel pass, pure gather-sum, unroll-4 =================
// Each pass covers 64 of the 128 channels: 8 lanes/node x 16 B = one full 128 B line
// per gathered row-strip (100% line utilization). Pass working set = 12.8 MB (vs 25.6),
// tightening the concurrent ascending-src sweep window into per-XCD L2 capacity.
__global__ __launch_bounds__(256) void k_agg(
    const uint16_t* __restrict__ hw2, const int* __restrict__ off,
    const int* __restrict__ csrs, const float* __restrict__ inv,
    const int* __restrict__ order,
    uint16_t* __restrict__ hout, int do_relu, int half)
{
  int slot = blockIdx.x * 32 + (threadIdx.x >> 3);
  if (slot >= NN) return;
  int node = order[slot];
  int c = half * 64 + (threadIdx.x & 7) * 8;   // 8 channels = 16 B per lane

  uint4 sv = *(const uint4*)(hw2 + (size_t)node * HH + c);
  float a[8] = {0.f, 0.f, 0.f, 0.f, 0.f, 0.f, 0.f, 0.f};
  addrow(a, sv);                    // self term (already inv[node]-scaled)

  int e0 = off[node], e1 = off[node + 1];
  int e = e0;
  for (; e + 4 <= e1; e += 4) {
    int s0 = csrs[e + 0], s1 = csrs[e + 1], s2 = csrs[e + 2], s3 = csrs[e + 3];
    uint4 v0 = *(const uint4*)(hw2 + (size_t)s0 * HH + c);
    uint4 v1 = *(const uint4*)(hw2 + (size_t)s1 * HH + c);
    uint4 v2 = *(const uint4*)(hw2 + (size_t)s2 * HH + c);
    uint4 v3 = *(const uint4*)(hw2 + (size_t)s3 * HH + c);
    addrow(a, v0); addrow(a, v1); addrow(a, v2); addrow(a, v3);
  }
  for (; e < e1; ++e) {
    int s = csrs[e];
    uint4 v = *(const uint4*)(hw2 + (size_t)s * HH + c);
    addrow(a, v);
  }
  float invd = inv[node];
#pragma unroll
  for (int j = 0; j < 8; ++j) {
    a[j] *= invd;
    if (do_relu) a[j] = fmaxf(a[j], 0.f);
  }
  uint4 o;
  o.x = f2b(a[0]) | (f2b(a[1]) << 16);
  o.y = f2b(a[2]) | (f2b(a[3]) << 16);
  o.z = f2b(a[4]) | (f2b(a[5]) << 16);
  o.w = f2b(a[6]) | (f2b(a[7]) << 16);
  *(uint4*)(hout + (size_t)node * HH + c) = o;
}

// ================= fused pool + decoder: one block per graph, zero atomics =================
__global__ __launch_bounds__(256) void k_pooldec(
    const uint16_t* __restrict__ h, const int* __restrict__ gstart,
    const float* __restrict__ w1, const float* __restrict__ b1,
    const float* __restrict__ w2, const float* __restrict__ b2,
    float* __restrict__ out)
{
  __shared__ float red[16][132];   // +4 pad
  __shared__ float p[128], tmpv[128];
  int g = blockIdx.x;
  int tid = threadIdx.x;
  int slot = tid >> 4;
  int c = (tid & 15) * 8;

  int r0 = gstart[g], r1 = gstart[g + 1];
  float a[8] = {0.f, 0.f, 0.f, 0.f, 0.f, 0.f, 0.f, 0.f};
  for (int r = r0 + slot; r < r1; r += 16) {
    uint4 v = *(const uint4*)(h + (size_t)r * HH + c);
    a[0] += b2f(v.x & 0xFFFFu); a[1] += b2f(v.x >> 16);
    a[2] += b2f(v.y & 0xFFFFu); a[3] += b2f(v.y >> 16);
    a[4] += b2f(v.z & 0xFFFFu); a[5] += b2f(v.z >> 16);
    a[6] += b2f(v.w & 0xFFFFu); a[7] += b2f(v.w >> 16);
  }
  *(float4*)&red[slot][c]     = make_float4(a[0], a[1], a[2], a[3]);
  *(float4*)&red[slot][c + 4] = make_float4(a[4], a[5], a[6], a[7]);
  __syncthreads();
  if (tid < 128) {
    float s = 0.f;
#pragma unroll
    for (int k = 0; k < 16; ++k) s += red[k][tid];
    p[tid] = s;
  }
  __syncthreads();
  if (tid < 128) {
    float acc1 = b1[tid];
    for (int k = 0; k < 128; ++k) acc1 += p[k] * w1[k * 128 + tid];
    tmpv[tid] = fmaxf(acc1, 0.f);
  }
  __syncthreads();
  if (tid < 10) {
    float o = b2[tid];
    for (int k = 0; k < 128; ++k) o += tmpv[k] * w2[k * 10 + tid];
    out[g * 10 + tid] = o;
  }
}

extern "C" void kernel_launch(void* const* d_in, const int* in_sizes, int n_in,
                              void* d_out, int out_size, void* d_ws, size_t ws_size,
                              hipStream_t stream) {
  const float* x       = (const float*)d_in[0];
  const int*   eidx    = (const int*)d_in[1];
  const int*   src     = eidx;            // edge_index[0]
  const int*   dst     = eidx + NE;       // edge_index[1]
  const int*   batch   = (const int*)d_in[3];
  const float* enc_w1  = (const float*)d_in[4];
  const float* enc_b1  = (const float*)d_in[5];
  const float* enc_w2  = (const float*)d_in[6];
  const float* enc_b2  = (const float*)d_in[7];
  const float* conv_w  = (const float*)d_in[8];
  const float* conv_b  = (const float*)d_in[9];
  const float* dec_w1  = (const float*)d_in[10];
  const float* dec_b1  = (const float*)d_in[11];
  const float* dec_w2  = (const float*)d_in[12];
  const float* dec_b2  = (const float*)d_in[13];
  float* out = (float*)d_out;

  char* ws = (char*)d_ws;
  size_t o = 0;
  auto alloc = [&](size_t bytes) -> char* {
    char* p = ws + o;
    o += (bytes + 255) & ~(size_t)255;
    return p;
  };
  int*      off     = (int*)alloc((size_t)(NN + 1) * 4);
  int*      csrs    = (int*)alloc((size_t)NE * 4);
  float*    inv     = (float*)alloc((size_t)NN * 4);
  int*      blkcntA = (int*)alloc((size_t)NBLK * NB * 4);
  int*      poffA   = (int*)alloc((size_t)NBLK * NB * 4);
  int*      blkcntB = (int*)alloc((size_t)NBLK * NB * 4);
  int*      poffB   = (int*)alloc((size_t)NBLK * NB * 4);
  int*      gbaseA  = (int*)alloc((size_t)(NB + 1) * 4);
  int*      gbaseB  = (int*)alloc((size_t)(NB + 1) * 4);
  int*      dhist2  = (int*)alloc((size_t)NB * 64 * 4);
  int*      dcur    = (int*)alloc(64 * 4);
  int*      order   = (int*)alloc((size_t)NN * 4);
  int*      gstart  = (int*)alloc((size_t)(NG + 1) * 4);
  uint16_t* buf0    = (uint16_t*)alloc((size_t)NN * HH * 2);
  uint16_t* buf1    = (uint16_t*)alloc((size_t)NN * HH * 2);
  uint2*    pairsA  = (uint2*)buf1;                          // 12.8 MB, dead before encoder
  uint32_t* pairB   = (uint32_t*)((char*)buf1 + (size_t)NE * 8);  // +6.4 MB, still < 25.6 MB

  // CSR build: sort by src-bucket, then stable by dst-bucket, then per-bucket by dst node
  k_cntA<<<dim3(NBLK), dim3(256), 0, stream>>>(src, blkcntA);
  k_scan<<<dim3(1), dim3(256), 0, stream>>>(blkcntA, poffA, gbaseA, off, 0);
  k_placeA<<<dim3(NBLK), dim3(256), 0, stream>>>(src, dst, poffA, gbaseA, pairsA);
  k_cntB<<<dim3(NBLK), dim3(256), 0, stream>>>(pairsA, blkcntB);
  k_scan<<<dim3(1), dim3(256), 0, stream>>>(blkcntB, poffB, gbaseB, off, 1);
  k_placeB<<<dim3(NBLK), dim3(256), 0, stream>>>(pairsA, poffB, gbaseB, pairB);
  k_bucket_sort<<<dim3(NB), dim3(256), 0, stream>>>(pairB, gbaseB, batch, off, inv, csrs,
                                                    dhist2, gstart);

  // degree-LPT order
  const int NBK = (NN + 255) / 256;
  k_dscan<<<dim3(1), dim3(64), 0, stream>>>(dhist2, dcur);
  k_dplace<<<dim3(NBK), dim3(256), 0, stream>>>(off, dcur, order);

  // encoder GEMM1 (fp32 x), then fused [enc2 + conv0 + prescale]
  const int GB = (NN + 127) / 128;   // 782
  k_gemm<<<dim3(GB), dim3(256), 0, stream>>>(nullptr, x, enc_w1, enc_b1, nullptr, buf1, NN, 1);
  k_gemm_dual<<<dim3(GB), dim3(256), 0, stream>>>(buf1, enc_w2, enc_b2,
                                                  conv_w + 0 * 16384, conv_b + 0,
                                                  inv, buf0, NN);

  // GCN layers: two half-channel agg passes alternating with prescaled conv GEMMs
  const int AB2 = NN / 32;   // 3125 (32 nodes/block, 8 lanes/node)
  k_agg <<<dim3(AB2), dim3(256), 0, stream>>>(buf0, off, csrs, inv, order, buf1, 1, 0);
  k_agg <<<dim3(AB2), dim3(256), 0, stream>>>(buf0, off, csrs, inv, order, buf1, 1, 1);
  k_gemm<<<dim3(GB), dim3(256), 0, stream>>>(buf1, nullptr, conv_w + 1 * 16384, conv_b + 128, inv, buf0, NN, 0);
  k_agg <<<dim3(AB2), dim3(256), 0, stream>>>(buf0, off, csrs, inv, order, buf1, 1, 0);
  k_agg <<<dim3(AB2), dim3(256), 0, stream>>>(buf0, off, csrs, inv, order, buf1, 1, 1);
  k_gemm<<<dim3(GB), dim3(256), 0, stream>>>(buf1, nullptr, conv_w + 2 * 16384, conv_b + 256, inv, buf0, NN, 0);
  k_agg <<<dim3(AB2), dim3(256), 0, stream>>>(buf0, off, csrs, inv, order, buf1, 0, 0);
  k_agg <<<dim3(AB2), dim3(256), 0, stream>>>(buf0, off, csrs, inv, order, buf1, 0, 1);

  // fused pool + decoder
  k_pooldec<<<dim3(NG), dim3(256), 0, stream>>>(buf1, gstart, dec_w1, dec_b1, dec_w2, dec_b2, out);
}